// Round 5
// baseline (524.544 us; speedup 1.0000x reference)
//
#include <hip/hip_runtime.h>
#include <hip/hip_bf16.h>

#define N_NODES 50000
#define N_EDGES 800000
#define IN_F 256
#define OUT_F 64
#define NBUCKET 196           // ceil(50000/256) dst-range buckets of 256 nodes
#define HCOPIES 32            // histogram copies per side (src/dst)
#define EDGES_PER_COPY 25000  // 800000/32
#define HWORDS 25000          // 50000 u16 counters packed into u32 words
#define PBLOCKS 200
#define EDGES_PER_PBLOCK 4000 // 200*4000 = 800000

// ---- LDS-privatized degree histogram: 64 blocks (32 src copies + 32 dst copies) ----
__global__ __launch_bounds__(1024)
void hist_kernel(const int* __restrict__ src, const int* __restrict__ dst,
                 unsigned* __restrict__ scratch) {
    __shared__ unsigned lh[HWORDS];   // 100KB: 50000 u16 counters packed
    int tid = threadIdx.x, b = blockIdx.x;
    const int* idx = (b < HCOPIES) ? src : dst;
    int k = b & 31;
    int e0 = k * EDGES_PER_COPY;
    for (int i = tid; i < HWORDS; i += 1024) lh[i] = 0;
    __syncthreads();
    for (int i = tid; i < EDGES_PER_COPY; i += 1024) {
        int id = idx[e0 + i];
        atomicAdd(&lh[id >> 1], (id & 1) ? 0x10000u : 1u);  // max 25000 per half, no carry
    }
    __syncthreads();
    unsigned* outp = scratch + (size_t)b * HWORDS;
    for (int i = tid; i < HWORDS; i += 1024) outp[i] = lh[i];
}

// ---- reduce 32 copies -> cnt_out / cnt_in ----
__global__ void reduce_kernel(const unsigned* __restrict__ scratch,
                              int* __restrict__ cnt_out, int* __restrict__ cnt_in) {
    int t = blockIdx.x * blockDim.x + threadIdx.x;
    if (t >= 2 * HWORDS) return;
    int side = (t >= HWORDS);
    int j = side ? t - HWORDS : t;
    const unsigned* base = scratch + (size_t)(side ? HCOPIES : 0) * HWORDS + j;
    unsigned lo = 0, hi = 0;
    for (int k = 0; k < HCOPIES; ++k) {
        unsigned v = base[(size_t)k * HWORDS];
        lo += v & 0xFFFFu; hi += v >> 16;
    }
    int* dstp = side ? cnt_in : cnt_out;
    dstp[2 * j] = (int)lo;
    dstp[2 * j + 1] = (int)hi;
}

// ---- bucket sizes from cnt_in -> exclusive scan -> bucket_off / bucket_cursor ----
__global__ void scan_kernel(const int* __restrict__ cnt_in,
                            int* __restrict__ bucket_off, int* __restrict__ bucket_cursor) {
    __shared__ int tot[256];
    int t = threadIdx.x;
    int s = 0;
    if (t < NBUCKET) {
        int base = t * 256;
        int lim = min(256, N_NODES - base);
        for (int i = 0; i < lim; ++i) s += cnt_in[base + i];
    }
    tot[t] = s;
    __syncthreads();
    for (int off = 1; off < 256; off <<= 1) {
        int v = (t >= off) ? tot[t - off] : 0;
        __syncthreads();
        tot[t] += v;
        __syncthreads();
    }
    if (t < NBUCKET) {
        int excl = tot[t] - s;
        bucket_off[t] = excl;
        bucket_cursor[t * 16] = excl;   // each cursor on its own 64B line
    }
    if (t == NBUCKET - 1) bucket_off[NBUCKET] = tot[t];
}

// ---- partition edges into dst-range buckets (LDS-ranked, stream-local writes) ----
__global__ __launch_bounds__(1024)
void partition_kernel(const int* __restrict__ src, const int* __restrict__ dst,
                      int* __restrict__ bucket_cursor, unsigned* __restrict__ recs) {
    __shared__ int lcnt[NBUCKET], lbase[NBUCKET];
    int tid = threadIdx.x;
    int e0 = blockIdx.x * EDGES_PER_PBLOCK;
    if (tid < NBUCKET) lcnt[tid] = 0;
    __syncthreads();
    unsigned rec[4]; int bkt[4], rnk[4];
#pragma unroll
    for (int j = 0; j < 4; ++j) {
        int i = j * 1024 + tid;
        bkt[j] = -1;
        if (i < EDGES_PER_PBLOCK) {
            int e = e0 + i;
            int s = src[e], d = dst[e];
            bkt[j] = d >> 8;
            rec[j] = (unsigned)s | ((unsigned)(d & 255) << 16);
            rnk[j] = atomicAdd(&lcnt[bkt[j]], 1);
        }
    }
    __syncthreads();
    if (tid < NBUCKET) lbase[tid] = atomicAdd(&bucket_cursor[tid * 16], lcnt[tid]);
    __syncthreads();
#pragma unroll
    for (int j = 0; j < 4; ++j)
        if (bkt[j] >= 0) recs[lbase[bkt[j]] + rnk[j]] = rec[j];
}

// ---- h = (feat * outdeg^-1/2) @ W, bf16 output ----
__global__ __launch_bounds__(256)
void gemm_kernel(const float* __restrict__ feat, const float* __restrict__ weight,
                 const int* __restrict__ cnt_out, __hip_bfloat16* __restrict__ h) {
    __shared__ __align__(16) float As[64 * 64];
    __shared__ __align__(16) float Ws[64 * 64];
    int tid = threadIdx.x;
    int block_row = blockIdx.x * 64;
    int cg = tid & 31;
    int rg = tid >> 5;
    float acc[8][2] = {};

    for (int kt = 0; kt < 4; ++kt) {
#pragma unroll
        for (int j = 0; j < 4; ++j) {
            int ldi = j * 256 + tid;
            int row = ldi >> 4;
            int c4  = ldi & 15;
            int grow = block_row + row;
            int grc = (grow < N_NODES) ? grow : (N_NODES - 1);
            float4 a = *(const float4*)&feat[grc * IN_F + kt * 64 + c4 * 4];
            float sc = rsqrtf((float)max(cnt_out[grc], 1));
            a.x *= sc; a.y *= sc; a.z *= sc; a.w *= sc;
            *(float4*)&As[row * 64 + c4 * 4] = a;
            float4 wv = *(const float4*)&weight[(kt * 64 + row) * OUT_F + c4 * 4];
            *(float4*)&Ws[row * 64 + c4 * 4] = wv;
        }
        __syncthreads();
#pragma unroll
        for (int kk4 = 0; kk4 < 16; ++kk4) {
            float4 a[8];
#pragma unroll
            for (int i = 0; i < 8; ++i)
                a[i] = *(const float4*)&As[(rg * 8 + i) * 64 + kk4 * 4];
#pragma unroll
            for (int j = 0; j < 4; ++j) {
                float w0 = Ws[(kk4 * 4 + j) * 64 + cg];
                float w1 = Ws[(kk4 * 4 + j) * 64 + cg + 32];
#pragma unroll
                for (int i = 0; i < 8; ++i) {
                    float av = (&a[i].x)[j];
                    acc[i][0] = fmaf(av, w0, acc[i][0]);
                    acc[i][1] = fmaf(av, w1, acc[i][1]);
                }
            }
        }
        __syncthreads();
    }
#pragma unroll
    for (int i = 0; i < 8; ++i) {
        int row = block_row + rg * 8 + i;
        if (row < N_NODES) {
            h[row * OUT_F + cg]      = __float2bfloat16(acc[i][0]);
            h[row * OUT_F + cg + 32] = __float2bfloat16(acc[i][1]);
        }
    }
}

// ---- aggregate: one block per bucket, 256x64 fp32 LDS accumulator ----
__global__ __launch_bounds__(1024)
void aggregate_kernel(const __hip_bfloat16* __restrict__ h, const unsigned* __restrict__ recs,
                      const int* __restrict__ bucket_off, const int* __restrict__ cnt_in,
                      const float* __restrict__ bias, float* __restrict__ out) {
    __shared__ float acc[256 * OUT_F];  // 64KB
    int tid = threadIdx.x, lane = tid & 63, w = tid >> 6;
    int b = blockIdx.x;
    for (int i = tid; i < 256 * OUT_F; i += 1024) acc[i] = 0.f;
    __syncthreads();
    int start = bucket_off[b], end = bucket_off[b + 1];
    int n = end - start;
    for (int i0 = w * 4; i0 < n; i0 += 64) {
        int m = min(4, n - i0);
        float v[4]; int dl[4] = {0, 0, 0, 0};
#pragma unroll
        for (int j = 0; j < 4; ++j) {
            if (j < m) {
                unsigned rec = recs[start + i0 + j];
                int s = (int)(rec & 0xFFFFu);
                dl[j] = (int)((rec >> 16) & 255u);
                v[j] = __bfloat162float(h[s * OUT_F + lane]);
            }
        }
#pragma unroll
        for (int j = 0; j < 4; ++j)
            if (j < m) atomicAdd(&acc[dl[j] * OUT_F + lane], v[j]);
    }
    __syncthreads();
    float bv = bias[lane];
    int gbase = b * 256;
    for (int node = w; node < 256; node += 16) {
        int g = gbase + node;
        if (g < N_NODES) {
            float sc = rsqrtf((float)max(cnt_in[g], 1));
            out[g * OUT_F + lane] = fmaf(acc[node * OUT_F + lane], sc, bv);
        }
    }
}

extern "C" void kernel_launch(void* const* d_in, const int* in_sizes, int n_in,
                              void* d_out, int out_size, void* d_ws, size_t ws_size,
                              hipStream_t stream) {
    const float* feat   = (const float*)d_in[0];
    const float* weight = (const float*)d_in[1];
    const float* bias   = (const float*)d_in[2];
    const int*   src    = (const int*)d_in[3];
    const int*   dst    = (const int*)d_in[4];
    float* out = (float*)d_out;

    // ws layout (int units):
    // cnt_out[50000] | cnt_in[50000] | bucket_off[197] | pad | bucket_cursor[196*16]
    // | hist scratch[64*25000] | recs[800000] | h (bf16 50000*64)
    int* ws            = (int*)d_ws;
    int* cnt_out       = ws;
    int* cnt_in        = ws + 50000;
    int* bucket_off    = ws + 100000;              // 197 ints
    int* bucket_cursor = ws + 100224;              // 196*16 = 3136 ints (line-padded)
    unsigned* scratch  = (unsigned*)(ws + 103424); // 64*25000 = 1.6M words
    unsigned* recs     = (unsigned*)(ws + 1703424);
    __hip_bfloat16* h  = (__hip_bfloat16*)(ws + 2503424);

    hist_kernel<<<2 * HCOPIES, 1024, 0, stream>>>(src, dst, scratch);
    reduce_kernel<<<(2 * HWORDS + 1023) / 1024, 1024, 0, stream>>>(scratch, cnt_out, cnt_in);
    scan_kernel<<<1, 256, 0, stream>>>(cnt_in, bucket_off, bucket_cursor);
    partition_kernel<<<PBLOCKS, 1024, 0, stream>>>(src, dst, bucket_cursor, recs);
    gemm_kernel<<<(N_NODES + 63) / 64, 256, 0, stream>>>(feat, weight, cnt_out, h);
    aggregate_kernel<<<NBUCKET, 1024, 0, stream>>>(h, recs, bucket_off, cnt_in, bias, out);
}

// Round 7
// 198.210 us; speedup vs baseline: 2.6464x; 2.6464x over previous
//
#include <hip/hip_runtime.h>
#include <hip/hip_bf16.h>

#define N_NODES 50000
#define N_EDGES 800000
#define IN_F 256
#define OUT_F 64
#define NBUCKET 196           // ceil(50000/256) dst-range buckets of 256 nodes
#define HCOPIES 32            // histogram copies per side (src/dst)
#define EDGES_PER_COPY 25000  // 800000/32
#define HWORDS 25000          // 50000 u16 counters packed into u32 words
#define PBLOCKS 200
#define EDGES_PER_PBLOCK 4000 // 200*4000 = 800000
#define MAXB 6144             // bucket capacity (mean 4096, +32 sigma)

// ---- LDS-privatized degree histogram: 64 blocks (32 src copies + 32 dst copies) ----
__global__ __launch_bounds__(1024)
void hist_kernel(const int* __restrict__ src, const int* __restrict__ dst,
                 unsigned* __restrict__ scratch) {
    __shared__ unsigned lh[HWORDS];   // 100KB: 50000 u16 counters packed
    int tid = threadIdx.x, b = blockIdx.x;
    const int* idx = (b < HCOPIES) ? src : dst;
    int k = b & 31;
    int e0 = k * EDGES_PER_COPY;
    for (int i = tid; i < HWORDS; i += 1024) lh[i] = 0;
    __syncthreads();
    for (int i = tid; i < EDGES_PER_COPY; i += 1024) {
        int id = idx[e0 + i];
        atomicAdd(&lh[id >> 1], (id & 1) ? 0x10000u : 1u);  // int atomic: native ds_add
    }
    __syncthreads();
    unsigned* outp = scratch + (size_t)b * HWORDS;
    for (int i = tid; i < HWORDS; i += 1024) outp[i] = lh[i];
}

// ---- reduce 32 copies -> cnt_out / cnt_in ----
__global__ void reduce_kernel(const unsigned* __restrict__ scratch,
                              int* __restrict__ cnt_out, int* __restrict__ cnt_in) {
    int t = blockIdx.x * blockDim.x + threadIdx.x;
    if (t >= 2 * HWORDS) return;
    int side = (t >= HWORDS);
    int j = side ? t - HWORDS : t;
    const unsigned* base = scratch + (size_t)(side ? HCOPIES : 0) * HWORDS + j;
    unsigned lo = 0, hi = 0;
    for (int k = 0; k < HCOPIES; ++k) {
        unsigned v = base[(size_t)k * HWORDS];
        lo += v & 0xFFFFu; hi += v >> 16;
    }
    int* dstp = side ? cnt_in : cnt_out;
    dstp[2 * j] = (int)lo;
    dstp[2 * j + 1] = (int)hi;
}

// ---- bucket sizes from cnt_in -> exclusive scan -> bucket_off / bucket_cursor ----
__global__ void scan_kernel(const int* __restrict__ cnt_in,
                            int* __restrict__ bucket_off, int* __restrict__ bucket_cursor) {
    __shared__ int tot[256];
    int t = threadIdx.x;
    int s = 0;
    if (t < NBUCKET) {
        int base = t * 256;
        int lim = min(256, N_NODES - base);
        for (int i = 0; i < lim; ++i) s += cnt_in[base + i];
    }
    tot[t] = s;
    __syncthreads();
    for (int off = 1; off < 256; off <<= 1) {
        int v = (t >= off) ? tot[t - off] : 0;
        __syncthreads();
        tot[t] += v;
        __syncthreads();
    }
    if (t < NBUCKET) {
        int excl = tot[t] - s;
        bucket_off[t] = excl;
        bucket_cursor[t * 16] = excl;   // each cursor on its own 64B line
    }
    if (t == NBUCKET - 1) bucket_off[NBUCKET] = tot[t];
}

// ---- partition edges into dst-range buckets (LDS-ranked, stream-local writes) ----
__global__ __launch_bounds__(1024)
void partition_kernel(const int* __restrict__ src, const int* __restrict__ dst,
                      int* __restrict__ bucket_cursor, unsigned* __restrict__ recs) {
    __shared__ int lcnt[NBUCKET], lbase[NBUCKET];
    int tid = threadIdx.x;
    int e0 = blockIdx.x * EDGES_PER_PBLOCK;
    if (tid < NBUCKET) lcnt[tid] = 0;
    __syncthreads();
    unsigned rec[4]; int bkt[4], rnk[4];
#pragma unroll
    for (int j = 0; j < 4; ++j) {
        int i = j * 1024 + tid;
        bkt[j] = -1;
        if (i < EDGES_PER_PBLOCK) {
            int e = e0 + i;
            int s = src[e], d = dst[e];
            bkt[j] = d >> 8;
            rec[j] = (unsigned)s | ((unsigned)(d & 255) << 16);
            rnk[j] = atomicAdd(&lcnt[bkt[j]], 1);
        }
    }
    __syncthreads();
    if (tid < NBUCKET) lbase[tid] = atomicAdd(&bucket_cursor[tid * 16], lcnt[tid]);
    __syncthreads();
#pragma unroll
    for (int j = 0; j < 4; ++j)
        if (bkt[j] >= 0) recs[lbase[bkt[j]] + rnk[j]] = rec[j];
}

// ---- h = (feat * outdeg^-1/2) @ W, bf16 output ----
__global__ __launch_bounds__(256)
void gemm_kernel(const float* __restrict__ feat, const float* __restrict__ weight,
                 const int* __restrict__ cnt_out, __hip_bfloat16* __restrict__ h) {
    __shared__ __align__(16) float As[64 * 64];
    __shared__ __align__(16) float Ws[64 * 64];
    int tid = threadIdx.x;
    int block_row = blockIdx.x * 64;
    int cg = tid & 31;
    int rg = tid >> 5;
    float acc[8][2] = {};

    for (int kt = 0; kt < 4; ++kt) {
#pragma unroll
        for (int j = 0; j < 4; ++j) {
            int ldi = j * 256 + tid;
            int row = ldi >> 4;
            int c4  = ldi & 15;
            int grow = block_row + row;
            int grc = (grow < N_NODES) ? grow : (N_NODES - 1);
            float4 a = *(const float4*)&feat[grc * IN_F + kt * 64 + c4 * 4];
            float sc = rsqrtf((float)max(cnt_out[grc], 1));
            a.x *= sc; a.y *= sc; a.z *= sc; a.w *= sc;
            *(float4*)&As[row * 64 + c4 * 4] = a;
            float4 wv = *(const float4*)&weight[(kt * 64 + row) * OUT_F + c4 * 4];
            *(float4*)&Ws[row * 64 + c4 * 4] = wv;
        }
        __syncthreads();
#pragma unroll
        for (int kk4 = 0; kk4 < 16; ++kk4) {
            float4 a[8];
#pragma unroll
            for (int i = 0; i < 8; ++i)
                a[i] = *(const float4*)&As[(rg * 8 + i) * 64 + kk4 * 4];
#pragma unroll
            for (int j = 0; j < 4; ++j) {
                float w0 = Ws[(kk4 * 4 + j) * 64 + cg];
                float w1 = Ws[(kk4 * 4 + j) * 64 + cg + 32];
#pragma unroll
                for (int i = 0; i < 8; ++i) {
                    float av = (&a[i].x)[j];
                    acc[i][0] = fmaf(av, w0, acc[i][0]);
                    acc[i][1] = fmaf(av, w1, acc[i][1]);
                }
            }
        }
        __syncthreads();
    }
#pragma unroll
    for (int i = 0; i < 8; ++i) {
        int row = block_row + rg * 8 + i;
        if (row < N_NODES) {
            h[row * OUT_F + cg]      = __float2bfloat16(acc[i][0]);
            h[row * OUT_F + cg + 32] = __float2bfloat16(acc[i][1]);
        }
    }
}

// ---- aggregate: one block per bucket; counting-sort by local dst (int LDS atomics),
// ---- then one wave per node reduces in registers. NO float atomics anywhere. ----
__global__ __launch_bounds__(1024)
void aggregate_kernel(const __hip_bfloat16* __restrict__ h, const unsigned* __restrict__ recs,
                      const int* __restrict__ bucket_off,
                      const float* __restrict__ bias, float* __restrict__ out) {
    __shared__ int cnt[256], off[256], cur[256];
    __shared__ unsigned short order[MAXB];   // src ids, grouped by local dst
    int tid = threadIdx.x, lane = tid & 63, w = tid >> 6;
    int b = blockIdx.x;
    if (tid < 256) { cnt[tid] = 0; cur[tid] = 0; }
    __syncthreads();
    int start = bucket_off[b], end = bucket_off[b + 1];
    int n = end - start;

    // pass 1: count per local node (native int ds_add)
    for (int i = tid; i < n; i += 1024)
        atomicAdd(&cnt[(recs[start + i] >> 16) & 255u], 1);
    __syncthreads();

    // inclusive Hillis-Steele scan of cnt -> off (all threads hit barriers)
    if (tid < 256) off[tid] = cnt[tid];
    __syncthreads();
    for (int o = 1; o < 256; o <<= 1) {
        int y = (tid < 256 && tid >= o) ? off[tid - o] : 0;
        __syncthreads();
        if (tid < 256) off[tid] += y;
        __syncthreads();
    }

    // pass 2: rank-scatter src ids into contiguous per-node runs
    for (int i = tid; i < n; i += 1024) {
        unsigned rec = recs[start + i];
        int dl = (rec >> 16) & 255u;
        int r = atomicAdd(&cur[dl], 1);
        int pos = off[dl] - cnt[dl] + r;
        if (pos < MAXB) order[pos] = (unsigned short)(rec & 0xFFFFu);
    }
    __syncthreads();

    // phase 3: wave w reduces nodes w, w+16, ... fully in registers
    float bv = bias[lane];
    int gbase = b * 256;
    for (int nd = w; nd < 256; nd += 16) {
        int g = gbase + nd;
        if (g >= N_NODES) continue;
        int m = cnt[nd];
        int s0 = off[nd] - m;
        float acc = 0.f;
        int k = 0;
        for (; k + 4 <= m; k += 4) {
            int a0 = order[s0 + k], a1 = order[s0 + k + 1];
            int a2 = order[s0 + k + 2], a3 = order[s0 + k + 3];
            acc += __bfloat162float(h[a0 * OUT_F + lane]) + __bfloat162float(h[a1 * OUT_F + lane])
                 + __bfloat162float(h[a2 * OUT_F + lane]) + __bfloat162float(h[a3 * OUT_F + lane]);
        }
        for (; k < m; ++k) acc += __bfloat162float(h[order[s0 + k] * OUT_F + lane]);
        float sc = rsqrtf((float)max(m, 1));   // m == in-degree(g)
        out[g * OUT_F + lane] = fmaf(acc, sc, bv);
    }
}

extern "C" void kernel_launch(void* const* d_in, const int* in_sizes, int n_in,
                              void* d_out, int out_size, void* d_ws, size_t ws_size,
                              hipStream_t stream) {
    const float* feat   = (const float*)d_in[0];
    const float* weight = (const float*)d_in[1];
    const float* bias   = (const float*)d_in[2];
    const int*   src    = (const int*)d_in[3];
    const int*   dst    = (const int*)d_in[4];
    float* out = (float*)d_out;

    // ws layout (int units):
    // cnt_out[50000] | cnt_in[50000] | bucket_off[197] | pad | bucket_cursor[196*16]
    // | hist scratch[64*25000] | recs[800000] | h (bf16 50000*64)
    int* ws            = (int*)d_ws;
    int* cnt_out       = ws;
    int* cnt_in        = ws + 50000;
    int* bucket_off    = ws + 100000;              // 197 ints
    int* bucket_cursor = ws + 100224;              // 196*16 = 3136 ints (line-padded)
    unsigned* scratch  = (unsigned*)(ws + 103424); // 64*25000 = 1.6M words
    unsigned* recs     = (unsigned*)(ws + 1703424);
    __hip_bfloat16* h  = (__hip_bfloat16*)(ws + 2503424);

    hist_kernel<<<2 * HCOPIES, 1024, 0, stream>>>(src, dst, scratch);
    reduce_kernel<<<(2 * HWORDS + 1023) / 1024, 1024, 0, stream>>>(scratch, cnt_out, cnt_in);
    scan_kernel<<<1, 256, 0, stream>>>(cnt_in, bucket_off, bucket_cursor);
    partition_kernel<<<PBLOCKS, 1024, 0, stream>>>(src, dst, bucket_cursor, recs);
    gemm_kernel<<<(N_NODES + 63) / 64, 256, 0, stream>>>(feat, weight, cnt_out, h);
    aggregate_kernel<<<NBUCKET, 1024, 0, stream>>>(h, recs, bucket_off, bias, out);
}

// Round 9
// 179.469 us; speedup vs baseline: 2.9228x; 1.1044x over previous
//
#include <hip/hip_runtime.h>
#include <hip/hip_bf16.h>

#define N_NODES 50000
#define N_EDGES 800000
#define IN_F 256
#define OUT_F 64
#define NBUCKET 196           // ceil(50000/256) dst-range buckets of 256 nodes
#define HCOPIES 32            // histogram copies per side (src/dst)
#define EDGES_PER_COPY 25000  // 800000/32
#define HWORDS 25000          // 50000 u16 counters packed into u32 words
#define PBLOCKS 200
#define EDGES_PER_PBLOCK 4000 // 200*4000 = 800000
#define MAXB 6144             // bucket capacity (mean 4096, +32 sigma)

using bf16x8 = __attribute__((ext_vector_type(8))) short;
using f32x4  = __attribute__((ext_vector_type(4))) float;

// ---- LDS-privatized degree histogram: 64 blocks (32 src copies + 32 dst copies) ----
__global__ __launch_bounds__(1024)
void hist_kernel(const int* __restrict__ src, const int* __restrict__ dst,
                 unsigned* __restrict__ scratch) {
    __shared__ unsigned lh[HWORDS];   // 100KB: 50000 u16 counters packed
    int tid = threadIdx.x, b = blockIdx.x;
    const int* idx = (b < HCOPIES) ? src : dst;
    int k = b & 31;
    int e0 = k * EDGES_PER_COPY;
    for (int i = tid; i < HWORDS; i += 1024) lh[i] = 0;
    __syncthreads();
    for (int i = tid; i < EDGES_PER_COPY; i += 1024) {
        int id = idx[e0 + i];
        atomicAdd(&lh[id >> 1], (id & 1) ? 0x10000u : 1u);  // int atomic: native ds_add
    }
    __syncthreads();
    unsigned* outp = scratch + (size_t)b * HWORDS;
    for (int i = tid; i < HWORDS; i += 1024) outp[i] = lh[i];
}

// ---- reduce 32 copies -> cnt_out / cnt_in ----
__global__ void reduce_kernel(const unsigned* __restrict__ scratch,
                              int* __restrict__ cnt_out, int* __restrict__ cnt_in) {
    int t = blockIdx.x * blockDim.x + threadIdx.x;
    if (t >= 2 * HWORDS) return;
    int side = (t >= HWORDS);
    int j = side ? t - HWORDS : t;
    const unsigned* base = scratch + (size_t)(side ? HCOPIES : 0) * HWORDS + j;
    unsigned lo = 0, hi = 0;
    for (int k = 0; k < HCOPIES; ++k) {
        unsigned v = base[(size_t)k * HWORDS];
        lo += v & 0xFFFFu; hi += v >> 16;
    }
    int* dstp = side ? cnt_in : cnt_out;
    dstp[2 * j] = (int)lo;
    dstp[2 * j + 1] = (int)hi;
}

// ---- bucket sizes from cnt_in -> exclusive scan -> bucket_off / bucket_cursor ----
__global__ void scan_kernel(const int* __restrict__ cnt_in,
                            int* __restrict__ bucket_off, int* __restrict__ bucket_cursor) {
    __shared__ int tot[256];
    int t = threadIdx.x;
    int s = 0;
    if (t < NBUCKET) {
        int base = t * 256;
        int lim = min(256, N_NODES - base);
        for (int i = 0; i < lim; ++i) s += cnt_in[base + i];
    }
    tot[t] = s;
    __syncthreads();
    for (int off = 1; off < 256; off <<= 1) {
        int v = (t >= off) ? tot[t - off] : 0;
        __syncthreads();
        tot[t] += v;
        __syncthreads();
    }
    if (t < NBUCKET) {
        int excl = tot[t] - s;
        bucket_off[t] = excl;
        bucket_cursor[t * 16] = excl;   // each cursor on its own 64B line
    }
    if (t == NBUCKET - 1) bucket_off[NBUCKET] = tot[t];
}

// ---- partition edges into dst-range buckets (LDS-ranked, stream-local writes) ----
__global__ __launch_bounds__(1024)
void partition_kernel(const int* __restrict__ src, const int* __restrict__ dst,
                      int* __restrict__ bucket_cursor, unsigned* __restrict__ recs) {
    __shared__ int lcnt[NBUCKET], lbase[NBUCKET];
    int tid = threadIdx.x;
    int e0 = blockIdx.x * EDGES_PER_PBLOCK;
    if (tid < NBUCKET) lcnt[tid] = 0;
    __syncthreads();
    unsigned rec[4]; int bkt[4], rnk[4];
#pragma unroll
    for (int j = 0; j < 4; ++j) {
        int i = j * 1024 + tid;
        bkt[j] = -1;
        if (i < EDGES_PER_PBLOCK) {
            int e = e0 + i;
            int s = src[e], d = dst[e];
            bkt[j] = d >> 8;
            rec[j] = (unsigned)s | ((unsigned)(d & 255) << 16);
            rnk[j] = atomicAdd(&lcnt[bkt[j]], 1);
        }
    }
    __syncthreads();
    if (tid < NBUCKET) lbase[tid] = atomicAdd(&bucket_cursor[tid * 16], lcnt[tid]);
    __syncthreads();
#pragma unroll
    for (int j = 0; j < 4; ++j)
        if (bkt[j] >= 0) recs[lbase[bkt[j]] + rnk[j]] = rec[j];
}

// ---- h = (feat * outdeg^-1/2) @ W via bf16 MFMA 16x16x32 ----
// 256 threads = 4 waves; wave w computes rows [blk*64 + w*16, +16) x all 64 cols.
// A-fragments loaded directly from global (no LDS); W staged once in LDS,
// transposed + XOR-swizzled so each B-frag is one conflict-free ds_read_b128.
// No __syncthreads in the K-loop.
__global__ __launch_bounds__(256)
void gemm_kernel(const float* __restrict__ feat, const float* __restrict__ weight,
                 const int* __restrict__ cnt_out, __hip_bfloat16* __restrict__ h) {
    __shared__ __align__(16) short Wt[64 * 256];  // [n][k] bf16, swizzled; 32KB
    int tid = threadIdx.x;

    // stage W (256x64 fp32) -> Wt[n][k] bf16, byte addr ^= (n&7)<<4
#pragma unroll
    for (int it = 0; it < 16; ++it) {
        int idx = it * 256 + tid;          // float4 index in row-major W
        int k  = idx >> 4;                 // 16 float4 per k-row
        int n4 = (idx & 15) * 4;
        float4 wv = *(const float4*)&weight[k * OUT_F + n4];
#pragma unroll
        for (int j = 0; j < 4; ++j) {
            int n = n4 + j;
            __hip_bfloat16 bv = __float2bfloat16((&wv.x)[j]);
            int byte = (n * 512 + k * 2) ^ ((n & 7) << 4);
            *(short*)((char*)Wt + byte) = *(short*)&bv;
        }
    }

    int lane = tid & 63, w = tid >> 6;
    int rowbase = blockIdx.x * 64 + w * 16;
    int arow = rowbase + (lane & 15);
    int arc = min(arow, N_NODES - 1);
    float sc = rsqrtf((float)max(cnt_out[arc], 1));
    const float* ap = &feat[arc * IN_F + (lane >> 4) * 8];
    __syncthreads();

    f32x4 acc[4];
#pragma unroll
    for (int c = 0; c < 4; ++c) acc[c] = (f32x4){0.f, 0.f, 0.f, 0.f};

#pragma unroll
    for (int ks = 0; ks < 8; ++ks) {
        float4 a0 = *(const float4*)(ap + ks * 32);
        float4 a1 = *(const float4*)(ap + ks * 32 + 4);
        bf16x8 af;
#pragma unroll
        for (int j = 0; j < 4; ++j) {
            __hip_bfloat16 b0 = __float2bfloat16((&a0.x)[j] * sc);
            __hip_bfloat16 b1 = __float2bfloat16((&a1.x)[j] * sc);
            af[j]     = *(short*)&b0;
            af[j + 4] = *(short*)&b1;
        }
        int kb = ks * 64 + (lane >> 4) * 16;   // byte offset of this lane's k-slot
#pragma unroll
        for (int c = 0; c < 4; ++c) {
            int n = c * 16 + (lane & 15);
            int byte = (n * 512 + kb) ^ ((n & 7) << 4);
            bf16x8 bfv = *(const bf16x8*)((const char*)Wt + byte);
            acc[c] = __builtin_amdgcn_mfma_f32_16x16x32_bf16(af, bfv, acc[c], 0, 0, 0);
        }
    }

    // D: row = (lane>>4)*4 + r, col = lane&15 (m89-verified)
#pragma unroll
    for (int c = 0; c < 4; ++c) {
#pragma unroll
        for (int r = 0; r < 4; ++r) {
            int row = rowbase + (lane >> 4) * 4 + r;
            if (row < N_NODES)
                h[row * OUT_F + c * 16 + (lane & 15)] = __float2bfloat16(acc[c][r]);
        }
    }
}

// ---- aggregate: one block per bucket; counting-sort by local dst (int LDS atomics),
// ---- then one wave per node reduces in registers. NO float atomics anywhere. ----
__global__ __launch_bounds__(1024)
void aggregate_kernel(const __hip_bfloat16* __restrict__ h, const unsigned* __restrict__ recs,
                      const int* __restrict__ bucket_off,
                      const float* __restrict__ bias, float* __restrict__ out) {
    __shared__ int cnt[256], off[256], cur[256];
    __shared__ unsigned short order[MAXB];   // src ids, grouped by local dst
    int tid = threadIdx.x, lane = tid & 63, w = tid >> 6;
    int b = blockIdx.x;
    if (tid < 256) { cnt[tid] = 0; cur[tid] = 0; }
    __syncthreads();
    int start = bucket_off[b], end = bucket_off[b + 1];
    int n = end - start;

    // pass 1: count per local node (native int ds_add)
    for (int i = tid; i < n; i += 1024)
        atomicAdd(&cnt[(recs[start + i] >> 16) & 255u], 1);
    __syncthreads();

    // inclusive Hillis-Steele scan of cnt -> off (all threads hit barriers)
    if (tid < 256) off[tid] = cnt[tid];
    __syncthreads();
    for (int o = 1; o < 256; o <<= 1) {
        int y = (tid < 256 && tid >= o) ? off[tid - o] : 0;
        __syncthreads();
        if (tid < 256) off[tid] += y;
        __syncthreads();
    }

    // pass 2: rank-scatter src ids into contiguous per-node runs
    for (int i = tid; i < n; i += 1024) {
        unsigned rec = recs[start + i];
        int dl = (rec >> 16) & 255u;
        int r = atomicAdd(&cur[dl], 1);
        int pos = off[dl] - cnt[dl] + r;
        if (pos < MAXB) order[pos] = (unsigned short)(rec & 0xFFFFu);
    }
    __syncthreads();

    // phase 3: wave w reduces nodes w, w+16, ... fully in registers
    float bv = bias[lane];
    int gbase = b * 256;
    for (int nd = w; nd < 256; nd += 16) {
        int g = gbase + nd;
        if (g >= N_NODES) continue;
        int m = cnt[nd];
        int s0 = off[nd] - m;
        float acc = 0.f;
        int k = 0;
        for (; k + 4 <= m; k += 4) {
            int a0 = order[s0 + k], a1 = order[s0 + k + 1];
            int a2 = order[s0 + k + 2], a3 = order[s0 + k + 3];
            acc += __bfloat162float(h[a0 * OUT_F + lane]) + __bfloat162float(h[a1 * OUT_F + lane])
                 + __bfloat162float(h[a2 * OUT_F + lane]) + __bfloat162float(h[a3 * OUT_F + lane]);
        }
        for (; k < m; ++k) acc += __bfloat162float(h[order[s0 + k] * OUT_F + lane]);
        float sc = rsqrtf((float)max(m, 1));   // m == in-degree(g)
        out[g * OUT_F + lane] = fmaf(acc, sc, bv);
    }
}

extern "C" void kernel_launch(void* const* d_in, const int* in_sizes, int n_in,
                              void* d_out, int out_size, void* d_ws, size_t ws_size,
                              hipStream_t stream) {
    const float* feat   = (const float*)d_in[0];
    const float* weight = (const float*)d_in[1];
    const float* bias   = (const float*)d_in[2];
    const int*   src    = (const int*)d_in[3];
    const int*   dst    = (const int*)d_in[4];
    float* out = (float*)d_out;

    // ws layout (int units):
    // cnt_out[50000] | cnt_in[50000] | bucket_off[197] | pad | bucket_cursor[196*16]
    // | hist scratch[64*25000] | recs[800000] | h (bf16 50000*64)
    int* ws            = (int*)d_ws;
    int* cnt_out       = ws;
    int* cnt_in        = ws + 50000;
    int* bucket_off    = ws + 100000;              // 197 ints
    int* bucket_cursor = ws + 100224;              // 196*16 = 3136 ints (line-padded)
    unsigned* scratch  = (unsigned*)(ws + 103424); // 64*25000 = 1.6M words
    unsigned* recs     = (unsigned*)(ws + 1703424);
    __hip_bfloat16* h  = (__hip_bfloat16*)(ws + 2503424);

    hist_kernel<<<2 * HCOPIES, 1024, 0, stream>>>(src, dst, scratch);
    reduce_kernel<<<(2 * HWORDS + 1023) / 1024, 1024, 0, stream>>>(scratch, cnt_out, cnt_in);
    scan_kernel<<<1, 256, 0, stream>>>(cnt_in, bucket_off, bucket_cursor);
    partition_kernel<<<PBLOCKS, 1024, 0, stream>>>(src, dst, bucket_cursor, recs);
    gemm_kernel<<<(N_NODES + 63) / 64, 256, 0, stream>>>(feat, weight, cnt_out, h);
    aggregate_kernel<<<NBUCKET, 1024, 0, stream>>>(h, recs, bucket_off, bias, out);
}

// Round 10
// 163.452 us; speedup vs baseline: 3.2092x; 1.0980x over previous
//
#include <hip/hip_runtime.h>
#include <hip/hip_bf16.h>

#define N_NODES 50000
#define N_EDGES 800000
#define IN_F 256
#define OUT_F 64
#define NBUCKET 196           // ceil(50000/256) dst-range buckets of 256 nodes
#define CAPB 6144             // fixed bucket capacity (mean 4096, +32 sigma)
#define HCOPIES 32            // src-histogram copies
#define EDGES_PER_COPY 25000  // 800000/32
#define HWORDS 25000          // 50000 u16 counters packed into u32 words
#define PBLOCKS 200
#define EDGES_PER_PBLOCK 4000 // 200*4000 = 800000

using bf16x8 = __attribute__((ext_vector_type(8))) short;
using f32x4  = __attribute__((ext_vector_type(4))) float;

// ---- LDS-privatized out-degree histogram: 32 blocks (src side only) ----
__global__ __launch_bounds__(1024)
void hist_kernel(const int* __restrict__ src, unsigned* __restrict__ scratch) {
    __shared__ unsigned lh[HWORDS];   // 100KB: 50000 u16 counters packed
    int tid = threadIdx.x, b = blockIdx.x;
    int e0 = b * EDGES_PER_COPY;
    for (int i = tid; i < HWORDS; i += 1024) lh[i] = 0;
    __syncthreads();
    for (int i = tid; i < EDGES_PER_COPY; i += 1024) {
        int id = src[e0 + i];
        atomicAdd(&lh[id >> 1], (id & 1) ? 0x10000u : 1u);  // native int ds_add
    }
    __syncthreads();
    unsigned* outp = scratch + (size_t)b * HWORDS;
    for (int i = tid; i < HWORDS; i += 1024) outp[i] = lh[i];
}

// ---- reduce 32 copies -> cnt_out ----
__global__ void reduce_kernel(const unsigned* __restrict__ scratch,
                              int* __restrict__ cnt_out) {
    int j = blockIdx.x * blockDim.x + threadIdx.x;
    if (j >= HWORDS) return;
    unsigned lo = 0, hi = 0;
    for (int k = 0; k < HCOPIES; ++k) {
        unsigned v = scratch[(size_t)k * HWORDS + j];
        lo += v & 0xFFFFu; hi += v >> 16;
    }
    cnt_out[2 * j] = (int)lo;
    cnt_out[2 * j + 1] = (int)hi;
}

// ---- partition edges into fixed-capacity dst-range buckets (LDS-ranked) ----
// bucket_cursor[b*16] ends as the TRUE in-edge count of bucket b.
__global__ __launch_bounds__(1024)
void partition_kernel(const int* __restrict__ src, const int* __restrict__ dst,
                      int* __restrict__ bucket_cursor, unsigned* __restrict__ recs) {
    __shared__ int lcnt[NBUCKET], lbase[NBUCKET];
    int tid = threadIdx.x;
    int e0 = blockIdx.x * EDGES_PER_PBLOCK;
    if (tid < NBUCKET) lcnt[tid] = 0;
    __syncthreads();
    unsigned rec[4]; int bkt[4], rnk[4];
#pragma unroll
    for (int j = 0; j < 4; ++j) {
        int i = j * 1024 + tid;
        bkt[j] = -1;
        if (i < EDGES_PER_PBLOCK) {
            int e = e0 + i;
            int s = src[e], d = dst[e];
            bkt[j] = d >> 8;
            rec[j] = (unsigned)s | ((unsigned)(d & 255) << 16);
            rnk[j] = atomicAdd(&lcnt[bkt[j]], 1);
        }
    }
    __syncthreads();
    if (tid < NBUCKET) lbase[tid] = atomicAdd(&bucket_cursor[tid * 16], lcnt[tid]);
    __syncthreads();
#pragma unroll
    for (int j = 0; j < 4; ++j) {
        if (bkt[j] >= 0) {
            int pos = lbase[bkt[j]] + rnk[j];
            if (pos < CAPB)   // overflow impossible at +32 sigma; clamp for safety
                recs[(size_t)bkt[j] * CAPB + pos] = rec[j];
        }
    }
}

// ---- h = (feat * outdeg^-1/2) @ W via bf16 MFMA 16x16x32 ----
// 256 threads = 4 waves; wave w computes rows [blk*64 + w*16, +16) x all 64 cols.
// A-fragments loaded directly from global (no LDS); W staged once in LDS,
// transposed + XOR-swizzled so each B-frag is one conflict-free ds_read_b128.
// No __syncthreads in the K-loop.
__global__ __launch_bounds__(256)
void gemm_kernel(const float* __restrict__ feat, const float* __restrict__ weight,
                 const int* __restrict__ cnt_out, __hip_bfloat16* __restrict__ h) {
    __shared__ __align__(16) short Wt[64 * 256];  // [n][k] bf16, swizzled; 32KB
    int tid = threadIdx.x;

    // stage W (256x64 fp32) -> Wt[n][k] bf16, byte addr ^= (n&7)<<4
#pragma unroll
    for (int it = 0; it < 16; ++it) {
        int idx = it * 256 + tid;          // float4 index in row-major W
        int k  = idx >> 4;                 // 16 float4 per k-row
        int n4 = (idx & 15) * 4;
        float4 wv = *(const float4*)&weight[k * OUT_F + n4];
#pragma unroll
        for (int j = 0; j < 4; ++j) {
            int n = n4 + j;
            __hip_bfloat16 bv = __float2bfloat16((&wv.x)[j]);
            int byte = (n * 512 + k * 2) ^ ((n & 7) << 4);
            *(short*)((char*)Wt + byte) = *(short*)&bv;
        }
    }

    int lane = tid & 63, w = tid >> 6;
    int rowbase = blockIdx.x * 64 + w * 16;
    int arow = rowbase + (lane & 15);
    int arc = min(arow, N_NODES - 1);
    float sc = rsqrtf((float)max(cnt_out[arc], 1));
    const float* ap = &feat[arc * IN_F + (lane >> 4) * 8];
    __syncthreads();

    f32x4 acc[4];
#pragma unroll
    for (int c = 0; c < 4; ++c) acc[c] = (f32x4){0.f, 0.f, 0.f, 0.f};

#pragma unroll
    for (int ks = 0; ks < 8; ++ks) {
        float4 a0 = *(const float4*)(ap + ks * 32);
        float4 a1 = *(const float4*)(ap + ks * 32 + 4);
        bf16x8 af;
#pragma unroll
        for (int j = 0; j < 4; ++j) {
            __hip_bfloat16 b0 = __float2bfloat16((&a0.x)[j] * sc);
            __hip_bfloat16 b1 = __float2bfloat16((&a1.x)[j] * sc);
            af[j]     = *(short*)&b0;
            af[j + 4] = *(short*)&b1;
        }
        int kb = ks * 64 + (lane >> 4) * 16;   // byte offset of this lane's k-slot
#pragma unroll
        for (int c = 0; c < 4; ++c) {
            int n = c * 16 + (lane & 15);
            int byte = (n * 512 + kb) ^ ((n & 7) << 4);
            bf16x8 bfv = *(const bf16x8*)((const char*)Wt + byte);
            acc[c] = __builtin_amdgcn_mfma_f32_16x16x32_bf16(af, bfv, acc[c], 0, 0, 0);
        }
    }

    // D: row = (lane>>4)*4 + r, col = lane&15 (m89-verified)
#pragma unroll
    for (int c = 0; c < 4; ++c) {
#pragma unroll
        for (int r = 0; r < 4; ++r) {
            int row = rowbase + (lane >> 4) * 4 + r;
            if (row < N_NODES)
                h[row * OUT_F + c * 16 + (lane & 15)] = __float2bfloat16(acc[c][r]);
        }
    }
}

// ---- aggregate: one block per bucket; counting-sort by local dst (int LDS atomics),
// ---- then one wave per node reduces in registers. NO float atomics anywhere. ----
__global__ __launch_bounds__(1024)
void aggregate_kernel(const __hip_bfloat16* __restrict__ h, const unsigned* __restrict__ recs,
                      const int* __restrict__ bucket_cursor,
                      const float* __restrict__ bias, float* __restrict__ out) {
    __shared__ int cnt[256], off[256], cur[256];
    __shared__ unsigned short order[CAPB];   // src ids, grouped by local dst
    int tid = threadIdx.x, lane = tid & 63, w = tid >> 6;
    int b = blockIdx.x;
    if (tid < 256) { cnt[tid] = 0; cur[tid] = 0; }
    __syncthreads();
    size_t start = (size_t)b * CAPB;
    int n = min(bucket_cursor[b * 16], CAPB);

    // pass 1: count per local node (native int ds_add)
    for (int i = tid; i < n; i += 1024)
        atomicAdd(&cnt[(recs[start + i] >> 16) & 255u], 1);
    __syncthreads();

    // inclusive Hillis-Steele scan of cnt -> off (all threads hit barriers)
    if (tid < 256) off[tid] = cnt[tid];
    __syncthreads();
    for (int o = 1; o < 256; o <<= 1) {
        int y = (tid < 256 && tid >= o) ? off[tid - o] : 0;
        __syncthreads();
        if (tid < 256) off[tid] += y;
        __syncthreads();
    }

    // pass 2: rank-scatter src ids into contiguous per-node runs
    for (int i = tid; i < n; i += 1024) {
        unsigned rec = recs[start + i];
        int dl = (rec >> 16) & 255u;
        int r = atomicAdd(&cur[dl], 1);
        int pos = off[dl] - cnt[dl] + r;
        order[pos] = (unsigned short)(rec & 0xFFFFu);
    }
    __syncthreads();

    // phase 3: wave w reduces nodes w, w+16, ... fully in registers
    float bv = bias[lane];
    int gbase = b * 256;
    for (int nd = w; nd < 256; nd += 16) {
        int g = gbase + nd;
        if (g >= N_NODES) continue;
        int m = cnt[nd];
        int s0 = off[nd] - m;
        float acc = 0.f;
        int k = 0;
        for (; k + 4 <= m; k += 4) {
            int a0 = order[s0 + k], a1 = order[s0 + k + 1];
            int a2 = order[s0 + k + 2], a3 = order[s0 + k + 3];
            acc += __bfloat162float(h[a0 * OUT_F + lane]) + __bfloat162float(h[a1 * OUT_F + lane])
                 + __bfloat162float(h[a2 * OUT_F + lane]) + __bfloat162float(h[a3 * OUT_F + lane]);
        }
        for (; k < m; ++k) acc += __bfloat162float(h[order[s0 + k] * OUT_F + lane]);
        float sc = rsqrtf((float)max(m, 1));   // m == in-degree(g)
        out[g * OUT_F + lane] = fmaf(acc, sc, bv);
    }
}

extern "C" void kernel_launch(void* const* d_in, const int* in_sizes, int n_in,
                              void* d_out, int out_size, void* d_ws, size_t ws_size,
                              hipStream_t stream) {
    const float* feat   = (const float*)d_in[0];
    const float* weight = (const float*)d_in[1];
    const float* bias   = (const float*)d_in[2];
    const int*   src    = (const int*)d_in[3];
    const int*   dst    = (const int*)d_in[4];
    float* out = (float*)d_out;

    // ws layout (int units):
    // cnt_out[50000] (pad to 50048) | bucket_cursor[196*16=3136] |
    // hist scratch[32*25000=800000] | recs[196*6144=1204224] | h (bf16 50000*64)
    int* ws            = (int*)d_ws;
    int* cnt_out       = ws;
    int* bucket_cursor = ws + 50048;
    unsigned* scratch  = (unsigned*)(ws + 53248);
    unsigned* recs     = (unsigned*)(ws + 853248);
    __hip_bfloat16* h  = (__hip_bfloat16*)(ws + 2057472);

    hipMemsetAsync(bucket_cursor, 0, 3136 * sizeof(int), stream);

    hist_kernel<<<HCOPIES, 1024, 0, stream>>>(src, scratch);
    reduce_kernel<<<(HWORDS + 1023) / 1024, 1024, 0, stream>>>(scratch, cnt_out);
    partition_kernel<<<PBLOCKS, 1024, 0, stream>>>(src, dst, bucket_cursor, recs);
    gemm_kernel<<<(N_NODES + 63) / 64, 256, 0, stream>>>(feat, weight, cnt_out, h);
    aggregate_kernel<<<NBUCKET, 1024, 0, stream>>>(h, recs, bucket_cursor, bias, out);
}

// Round 16
// 162.110 us; speedup vs baseline: 3.2357x; 1.0083x over previous
//
#include <hip/hip_runtime.h>
#include <hip/hip_bf16.h>

#define N_NODES 50000
#define N_EDGES 800000
#define IN_F 256
#define OUT_F 64
#define NBUCKET 196           // ceil(50000/256) dst-range buckets of 256 nodes
#define CAPB 6144             // fixed bucket capacity (mean 4096, +32 sigma)
#define HCOPIES 32            // src-histogram copies
#define EDGES_PER_COPY 25000  // 800000/32
#define HWORDS 25000          // 50000 u16 counters packed into u32 words
#define PBLOCKS 200
#define EDGES_PER_PBLOCK 4000 // 200*4000 = 800000

using bf16x8 = __attribute__((ext_vector_type(8))) short;
using f32x4  = __attribute__((ext_vector_type(4))) float;

// ---- LDS-privatized out-degree histogram, direct packed atomic flush ----
// cnt_out_packed[j] holds counts of nodes 2j (lo16) and 2j+1 (hi16).
// No carry risk: max out-degree ~45 << 65536.
__global__ __launch_bounds__(1024)
void hist_kernel(const int* __restrict__ src, unsigned* __restrict__ cnt_out_packed) {
    __shared__ unsigned lh[HWORDS];   // 100KB: 50000 u16 counters packed
    int tid = threadIdx.x, b = blockIdx.x;
    int e0 = b * EDGES_PER_COPY;
    for (int i = tid; i < HWORDS; i += 1024) lh[i] = 0;
    __syncthreads();
    for (int i = tid; i < EDGES_PER_COPY; i += 1024) {
        int id = src[e0 + i];
        atomicAdd(&lh[id >> 1], (id & 1) ? 0x10000u : 1u);  // native int ds_add
    }
    __syncthreads();
    for (int i = tid; i < HWORDS; i += 1024) {
        unsigned v = lh[i];
        if (v) atomicAdd(&cnt_out_packed[i], v);  // coalesced L2 atomics
    }
}

// ---- partition edges into fixed-capacity dst-range buckets (LDS-ranked) ----
// bucket_cursor[b*16] ends as the TRUE in-edge count of bucket b.
__global__ __launch_bounds__(1024)
void partition_kernel(const int* __restrict__ src, const int* __restrict__ dst,
                      int* __restrict__ bucket_cursor, unsigned* __restrict__ recs) {
    __shared__ int lcnt[NBUCKET], lbase[NBUCKET];
    int tid = threadIdx.x;
    int e0 = blockIdx.x * EDGES_PER_PBLOCK;
    if (tid < NBUCKET) lcnt[tid] = 0;
    __syncthreads();
    unsigned rec[4]; int bkt[4], rnk[4];
#pragma unroll
    for (int j = 0; j < 4; ++j) {
        int i = j * 1024 + tid;
        bkt[j] = -1;
        if (i < EDGES_PER_PBLOCK) {
            int e = e0 + i;
            int s = src[e], d = dst[e];
            bkt[j] = d >> 8;
            rec[j] = (unsigned)s | ((unsigned)(d & 255) << 16);
            rnk[j] = atomicAdd(&lcnt[bkt[j]], 1);
        }
    }
    __syncthreads();
    if (tid < NBUCKET) lbase[tid] = atomicAdd(&bucket_cursor[tid * 16], lcnt[tid]);
    __syncthreads();
#pragma unroll
    for (int j = 0; j < 4; ++j) {
        if (bkt[j] >= 0) {
            int pos = lbase[bkt[j]] + rnk[j];
            if (pos < CAPB)   // overflow impossible at +32 sigma; clamp for safety
                recs[(size_t)bkt[j] * CAPB + pos] = rec[j];
        }
    }
}

// ---- h = (feat * outdeg^-1/2) @ W via bf16 MFMA 16x16x32 ----
// 256 threads = 4 waves; wave w computes rows [blk*64 + w*16, +16) x all 64 cols.
// A-fragments loaded directly from global (no LDS); W staged once in LDS via
// coalesced column loads + swizzled ds_write_b128 (conflict-free), so each
// B-frag read is one conflict-free ds_read_b128. No __syncthreads in K-loop.
__global__ __launch_bounds__(256)
void gemm_kernel(const float* __restrict__ feat, const float* __restrict__ weight,
                 const unsigned* __restrict__ cnt_out_packed, __hip_bfloat16* __restrict__ h) {
    __shared__ __align__(16) short Wt[64 * 256];  // [n][k] bf16, swizzled; 32KB
    int tid = threadIdx.x;

    // stage W (256x64 fp32) -> Wt[n][k] bf16; 2048 b128 writes, 8 per thread.
    // slot = it*256+tid: n = slot&63, k8 = slot>>6 (8 consecutive k per write).
#pragma unroll
    for (int it = 0; it < 8; ++it) {
        int slot = it * 256 + tid;
        int n  = slot & 63;
        int k8 = slot >> 6;           // 0..31
        bf16x8 v;
#pragma unroll
        for (int r = 0; r < 8; ++r) {
            // lanes n=0..63 consecutive -> coalesced 256B per r
            __hip_bfloat16 bv = __float2bfloat16(weight[(k8 * 8 + r) * OUT_F + n]);
            v[r] = *(short*)&bv;
        }
        int byte = (n * 512 + k8 * 16) ^ ((n & 7) << 4);
        *(bf16x8*)((char*)Wt + byte) = v;
    }

    int lane = tid & 63, w = tid >> 6;
    int rowbase = blockIdx.x * 64 + w * 16;
    int arow = rowbase + (lane & 15);
    int arc = min(arow, N_NODES - 1);
    unsigned pw = cnt_out_packed[arc >> 1];
    int deg = (arc & 1) ? (int)(pw >> 16) : (int)(pw & 0xFFFFu);
    float sc = rsqrtf((float)max(deg, 1));
    const float* ap = &feat[arc * IN_F + (lane >> 4) * 8];
    __syncthreads();

    f32x4 acc[4];
#pragma unroll
    for (int c = 0; c < 4; ++c) acc[c] = (f32x4){0.f, 0.f, 0.f, 0.f};

#pragma unroll
    for (int ks = 0; ks < 8; ++ks) {
        float4 a0 = *(const float4*)(ap + ks * 32);
        float4 a1 = *(const float4*)(ap + ks * 32 + 4);
        bf16x8 af;
#pragma unroll
        for (int j = 0; j < 4; ++j) {
            __hip_bfloat16 b0 = __float2bfloat16((&a0.x)[j] * sc);
            __hip_bfloat16 b1 = __float2bfloat16((&a1.x)[j] * sc);
            af[j]     = *(short*)&b0;
            af[j + 4] = *(short*)&b1;
        }
        int kb = ks * 64 + (lane >> 4) * 16;   // byte offset of this lane's k-slot
#pragma unroll
        for (int c = 0; c < 4; ++c) {
            int n = c * 16 + (lane & 15);
            int byte = (n * 512 + kb) ^ ((n & 7) << 4);
            bf16x8 bfv = *(const bf16x8*)((const char*)Wt + byte);
            acc[c] = __builtin_amdgcn_mfma_f32_16x16x32_bf16(af, bfv, acc[c], 0, 0, 0);
        }
    }

    // D: row = (lane>>4)*4 + r, col = lane&15 (m89-verified)
#pragma unroll
    for (int c = 0; c < 4; ++c) {
#pragma unroll
        for (int r = 0; r < 4; ++r) {
            int row = rowbase + (lane >> 4) * 4 + r;
            if (row < N_NODES)
                h[row * OUT_F + c * 16 + (lane & 15)] = __float2bfloat16(acc[c][r]);
        }
    }
}

// ---- aggregate: one block per bucket; counting-sort by local dst (int LDS atomics),
// ---- recs staged in registers (single global read); one wave per node reduces
// ---- in registers. NO float atomics anywhere. ----
__global__ __launch_bounds__(1024)
void aggregate_kernel(const __hip_bfloat16* __restrict__ h, const unsigned* __restrict__ recs,
                      const int* __restrict__ bucket_cursor,
                      const float* __restrict__ bias, float* __restrict__ out) {
    __shared__ int cnt[256], off[256], cur[256];
    __shared__ unsigned short order[CAPB];   // src ids, grouped by local dst
    int tid = threadIdx.x, lane = tid & 63, w = tid >> 6;
    int b = blockIdx.x;
    if (tid < 256) { cnt[tid] = 0; cur[tid] = 0; }
    __syncthreads();
    size_t start = (size_t)b * CAPB;
    int n = min(bucket_cursor[b * 16], CAPB);

    // single global read of this block's recs into registers (static unroll)
    unsigned myrec[6];
#pragma unroll
    for (int j = 0; j < 6; ++j) {
        int i = j * 1024 + tid;
        myrec[j] = (i < n) ? recs[start + i] : 0xFFFFFFFFu;
    }

    // pass 1: count per local node (native int ds_add)
#pragma unroll
    for (int j = 0; j < 6; ++j)
        if (myrec[j] != 0xFFFFFFFFu)
            atomicAdd(&cnt[(myrec[j] >> 16) & 255u], 1);
    __syncthreads();

    // inclusive Hillis-Steele scan of cnt -> off (all threads hit barriers)
    if (tid < 256) off[tid] = cnt[tid];
    __syncthreads();
    for (int o = 1; o < 256; o <<= 1) {
        int y = (tid < 256 && tid >= o) ? off[tid - o] : 0;
        __syncthreads();
        if (tid < 256) off[tid] += y;
        __syncthreads();
    }

    // pass 2: rank-scatter src ids into contiguous per-node runs
#pragma unroll
    for (int j = 0; j < 6; ++j) {
        if (myrec[j] != 0xFFFFFFFFu) {
            int dl = (myrec[j] >> 16) & 255u;
            int r = atomicAdd(&cur[dl], 1);
            order[off[dl] - cnt[dl] + r] = (unsigned short)(myrec[j] & 0xFFFFu);
        }
    }
    __syncthreads();

    // phase 3: wave w reduces nodes w, w+16, ... fully in registers
    float bv = bias[lane];
    int gbase = b * 256;
    for (int nd = w; nd < 256; nd += 16) {
        int g = gbase + nd;
        if (g >= N_NODES) continue;
        int m = cnt[nd];
        int s0 = off[nd] - m;
        float acc = 0.f;
        int k = 0;
        for (; k + 4 <= m; k += 4) {
            int a0 = order[s0 + k], a1 = order[s0 + k + 1];
            int a2 = order[s0 + k + 2], a3 = order[s0 + k + 3];
            acc += __bfloat162float(h[a0 * OUT_F + lane]) + __bfloat162float(h[a1 * OUT_F + lane])
                 + __bfloat162float(h[a2 * OUT_F + lane]) + __bfloat162float(h[a3 * OUT_F + lane]);
        }
        for (; k < m; ++k) acc += __bfloat162float(h[order[s0 + k] * OUT_F + lane]);
        float sc = rsqrtf((float)max(m, 1));   // m == in-degree(g)
        out[g * OUT_F + lane] = fmaf(acc, sc, bv);
    }
}

extern "C" void kernel_launch(void* const* d_in, const int* in_sizes, int n_in,
                              void* d_out, int out_size, void* d_ws, size_t ws_size,
                              hipStream_t stream) {
    const float* feat   = (const float*)d_in[0];
    const float* weight = (const float*)d_in[1];
    const float* bias   = (const float*)d_in[2];
    const int*   src    = (const int*)d_in[3];
    const int*   dst    = (const int*)d_in[4];
    float* out = (float*)d_out;

    // ws layout (int units):
    // cnt_out_packed[25000] | bucket_cursor[196*16=3136] (one contiguous zero region)
    // | recs[196*6144=1204224] | h (bf16 50000*64)
    int* ws               = (int*)d_ws;
    unsigned* cnt_packed  = (unsigned*)ws;
    int* bucket_cursor    = ws + 25000;
    unsigned* recs        = (unsigned*)(ws + 28160);
    __hip_bfloat16* h     = (__hip_bfloat16*)(ws + 28160 + (size_t)NBUCKET * CAPB);

    hipMemsetAsync(cnt_packed, 0, 28136 * sizeof(int), stream);  // cnt + cursors

    hist_kernel<<<HCOPIES, 1024, 0, stream>>>(src, cnt_packed);
    partition_kernel<<<PBLOCKS, 1024, 0, stream>>>(src, dst, bucket_cursor, recs);
    gemm_kernel<<<(N_NODES + 63) / 64, 256, 0, stream>>>(feat, weight, cnt_packed, h);
    aggregate_kernel<<<NBUCKET, 1024, 0, stream>>>(h, recs, bucket_cursor, bias, out);
}